// Round 4
// baseline (759.836 us; speedup 1.0000x reference)
//
#include <hip/hip_runtime.h>

#define D 128
#define BSH 7              // nodes per bucket = 128
#define CPAD 16            // pad bucket counters to 1 per 64B line

// ---------------- preprocessing: bucketed CSR build ----------------
// Assumes n <= 131072 (bucket count <= 1024) and src/dst < 2^17.

__global__ void k_zero(int* __restrict__ p, int n) {
  int i = blockIdx.x * 256 + threadIdx.x;
  if (i < n) p[i] = 0;
}

// count edges per dst-bucket (padded counters)
__global__ void k_bcount(const int* __restrict__ dst, int* __restrict__ bcnt, int E) {
  int e = blockIdx.x * 256 + threadIdx.x;
  if (e < E) atomicAdd(&bcnt[(dst[e] >> BSH) * CPAD], 1);
}

// single-block exclusive scan over B buckets (B <= 1024); init bfill = boff
__global__ void k_bscan(const int* __restrict__ bcnt, int* __restrict__ boff,
                        int* __restrict__ bfill, int B) {
  __shared__ int s[1024];
  int t = threadIdx.x;
  int v = (t < B) ? bcnt[t * CPAD] : 0;
  s[t] = v;
  __syncthreads();
  for (int off = 1; off < 1024; off <<= 1) {
    int x = (t >= off) ? s[t - off] : 0;
    __syncthreads();
    s[t] += x;
    __syncthreads();
  }
  if (t < B) {
    int e = s[t] - v;
    boff[t] = e;
    bfill[t * CPAD] = e;
  }
}

// scatter edges into bucket-contiguous storage, packed (src<<7)|(dst&127)
__global__ void k_bscatter(const int* __restrict__ src, const int* __restrict__ dst,
                           int* __restrict__ bfill, int* __restrict__ ebuf, int E) {
  int e = blockIdx.x * 256 + threadIdx.x;
  if (e < E) {
    int d = dst[e];
    int pos = atomicAdd(&bfill[(d >> BSH) * CPAD], 1);
    ebuf[pos] = (src[e] << BSH) | (d & 127);
  }
}

// per-bucket degree count via LDS atomics; coalesced indeg write
__global__ __launch_bounds__(256) void k_bdeg(const int* __restrict__ ebuf,
                                              const int* __restrict__ boff,
                                              const int* __restrict__ bcnt,
                                              int* __restrict__ indeg, int n) {
  __shared__ int cnt[128];
  int b = blockIdx.x, t = threadIdx.x;
  if (t < 128) cnt[t] = 0;
  __syncthreads();
  int s0 = boff[b], m = bcnt[b * CPAD];
  for (int i = t; i < m; i += 256) atomicAdd(&cnt[ebuf[s0 + i] & 127], 1);
  __syncthreads();
  int node = (b << BSH) + t;
  if (t < 128 && node < n) indeg[node] = cnt[t];
}

// block-level exclusive scan (256/block) over indeg
__global__ void k_scan1(const int* __restrict__ indeg, int* __restrict__ rp,
                        int* __restrict__ partials, int n) {
  __shared__ int s[256];
  int t = threadIdx.x;
  int i = blockIdx.x * 256 + t;
  int v = (i < n) ? indeg[i] : 0;
  s[t] = v;
  __syncthreads();
  for (int off = 1; off < 256; off <<= 1) {
    int x = (t >= off) ? s[t - off] : 0;
    __syncthreads();
    s[t] += x;
    __syncthreads();
  }
  if (i < n) rp[i] = s[t] - v;
  if (t == 255) partials[blockIdx.x] = s[255];
}

__global__ void k_scan2(int* __restrict__ partials, int nb) {
  __shared__ int s[512];
  int t = threadIdx.x;
  int v = (t < nb) ? partials[t] : 0;
  s[t] = v;
  __syncthreads();
  for (int off = 1; off < 512; off <<= 1) {
    int x = (t >= off) ? s[t - off] : 0;
    __syncthreads();
    s[t] += x;
    __syncthreads();
  }
  if (t < nb) partials[t] = s[t] - v;
}

__global__ void k_scan3(const int* __restrict__ indeg, int* __restrict__ rp,
                        const int* __restrict__ partials, float* __restrict__ dinv, int n) {
  int i = blockIdx.x * 256 + threadIdx.x;
  if (i < n) {
    rp[i] = rp[i] + partials[blockIdx.x];
    dinv[i] = rsqrtf((float)(indeg[i] + 1));
  }
}

// per-bucket CSR fill: LDS local fill counters + rp staged in LDS;
// csr writes confined to the bucket's contiguous range (lines written once)
__global__ __launch_bounds__(256) void k_bfill(const int* __restrict__ ebuf,
                                               const int* __restrict__ boff,
                                               const int* __restrict__ bcnt,
                                               const int* __restrict__ rp,
                                               int* __restrict__ csr, int n) {
  __shared__ int lc[128];
  __shared__ int lrp[128];
  int b = blockIdx.x, t = threadIdx.x;
  int base = b << BSH;
  if (t < 128) {
    lc[t] = 0;
    int node = base + t;
    lrp[t] = (node < n) ? rp[node] : 0;
  }
  __syncthreads();
  int s0 = boff[b], m = bcnt[b * CPAD];
  for (int i = t; i < m; i += 256) {
    int p = ebuf[s0 + i];
    int ln = p & 127;
    int l = atomicAdd(&lc[ln], 1);
    csr[lrp[ln] + l] = p >> BSH;
  }
}

// ---------------- GEMM: out[row] = dinv[row] * (X[gather(row)] @ W) ----------------

#define F4E(v, j) ((j) == 0 ? (v).x : ((j) == 1 ? (v).y : ((j) == 2 ? (v).z : (v).w)))

__global__ __launch_bounds__(256) void k_gemm(const float* __restrict__ X,
                                              const int* __restrict__ xidx,
                                              const float* __restrict__ W,
                                              const float* __restrict__ dinv,
                                              float* __restrict__ out, int n) {
  __shared__ float Xs[64 * D];   // 32 KB
  __shared__ float Ws[D * 64];   // 32 KB
  int tid = threadIdx.x;
  int r0 = blockIdx.x * 64;
  int c0 = blockIdx.y * 64;

  {
    const float4* W4 = (const float4*)W;
    float4* Ws4 = (float4*)Ws;
    for (int i = tid; i < 128 * 16; i += 256) {
      int k = i >> 4, cc = i & 15;
      Ws4[i] = W4[k * (D / 4) + (c0 >> 2) + cc];
    }
  }
  {
    float4* Xs4 = (float4*)Xs;
    const float4* X4 = (const float4*)X;
    for (int i = tid; i < 64 * 32; i += 256) {
      int r = i >> 5, kc = i & 31;
      int row = r0 + r;
      float4 v = make_float4(0.f, 0.f, 0.f, 0.f);
      if (row < n) {
        int srow = xidx ? xidx[row] : row;
        v = X4[srow * 32 + kc];
      }
      Xs4[i] = v;
    }
  }
  __syncthreads();

  int cg = (tid & 15) * 4;
  int rg = (tid >> 4) * 4;
  float acc[4][4] = {{0.f}};
  const float4* Xs4 = (const float4*)Xs;
  const float4* Ws4 = (const float4*)Ws;

#pragma unroll 4
  for (int k4 = 0; k4 < D; k4 += 4) {
    float4 a[4], w[4];
#pragma unroll
    for (int i = 0; i < 4; i++) a[i] = Xs4[((rg + i) * D + k4) >> 2];
#pragma unroll
    for (int kk = 0; kk < 4; kk++) w[kk] = Ws4[((k4 + kk) * 64 + cg) >> 2];
#pragma unroll
    for (int kk = 0; kk < 4; kk++)
#pragma unroll
      for (int i = 0; i < 4; i++)
#pragma unroll
        for (int j = 0; j < 4; j++)
          acc[i][j] += F4E(a[i], kk) * F4E(w[kk], j);
  }

#pragma unroll
  for (int i = 0; i < 4; i++) {
    int row = r0 + rg + i;
    if (row < n) {
      float sc = dinv[row];
      float4 o = make_float4(acc[i][0] * sc, acc[i][1] * sc,
                             acc[i][2] * sc, acc[i][3] * sc);
      ((float4*)out)[(row * D + c0 + cg) >> 2] = o;
    }
  }
}

// ---------------- aggregation ----------------
// out[d] = act(dinv[d]*(sum_{s->d} hs[s] + hs[d]) + b); 32-lane group per node,
// lane owns one float4. 8x unroll -> 8 independent gathers in flight.

__global__ __launch_bounds__(256) void k_agg(const float* __restrict__ hs,
                                             const int* __restrict__ rp,
                                             const int* __restrict__ indeg,
                                             const int* __restrict__ csr,
                                             const float* __restrict__ dinv,
                                             const float* __restrict__ bias,
                                             float* __restrict__ out, int n, int relu) {
  int lane = threadIdx.x & 31;
  int d = (blockIdx.x * 256 + threadIdx.x) >> 5;
  if (d >= n) return;
  const float4* hs4 = (const float4*)hs;
  float4 acc = hs4[d * 32 + lane];
  int start = rp[d];
  int cnt = indeg[d];
  const int* nb = csr + start;

  int e = 0;
  for (; e + 8 <= cnt; e += 8) {
    int s0 = nb[e],     s1 = nb[e + 1], s2 = nb[e + 2], s3 = nb[e + 3];
    int s4 = nb[e + 4], s5 = nb[e + 5], s6 = nb[e + 6], s7 = nb[e + 7];
    float4 v0 = hs4[s0 * 32 + lane];
    float4 v1 = hs4[s1 * 32 + lane];
    float4 v2 = hs4[s2 * 32 + lane];
    float4 v3 = hs4[s3 * 32 + lane];
    float4 v4 = hs4[s4 * 32 + lane];
    float4 v5 = hs4[s5 * 32 + lane];
    float4 v6 = hs4[s6 * 32 + lane];
    float4 v7 = hs4[s7 * 32 + lane];
    acc.x += ((v0.x + v1.x) + (v2.x + v3.x)) + ((v4.x + v5.x) + (v6.x + v7.x));
    acc.y += ((v0.y + v1.y) + (v2.y + v3.y)) + ((v4.y + v5.y) + (v6.y + v7.y));
    acc.z += ((v0.z + v1.z) + (v2.z + v3.z)) + ((v4.z + v5.z) + (v6.z + v7.z));
    acc.w += ((v0.w + v1.w) + (v2.w + v3.w)) + ((v4.w + v5.w) + (v6.w + v7.w));
  }
  for (; e + 4 <= cnt; e += 4) {
    int s0 = nb[e], s1 = nb[e + 1], s2 = nb[e + 2], s3 = nb[e + 3];
    float4 v0 = hs4[s0 * 32 + lane];
    float4 v1 = hs4[s1 * 32 + lane];
    float4 v2 = hs4[s2 * 32 + lane];
    float4 v3 = hs4[s3 * 32 + lane];
    acc.x += (v0.x + v1.x) + (v2.x + v3.x);
    acc.y += (v0.y + v1.y) + (v2.y + v3.y);
    acc.z += (v0.z + v1.z) + (v2.z + v3.z);
    acc.w += (v0.w + v1.w) + (v2.w + v3.w);
  }
  for (; e < cnt; e++) {
    float4 v = hs4[nb[e] * 32 + lane];
    acc.x += v.x; acc.y += v.y; acc.z += v.z; acc.w += v.w;
  }

  float sc = dinv[d];
  float4 bv = ((const float4*)bias)[lane];
  float4 o;
  o.x = sc * acc.x + bv.x;
  o.y = sc * acc.y + bv.y;
  o.z = sc * acc.z + bv.z;
  o.w = sc * acc.w + bv.w;
  if (relu) {
    o.x = fmaxf(o.x, 0.f); o.y = fmaxf(o.y, 0.f);
    o.z = fmaxf(o.z, 0.f); o.w = fmaxf(o.w, 0.f);
  }
  ((float4*)out)[d * 32 + lane] = o;
}

// ---------------- launcher ----------------

extern "C" void kernel_launch(void* const* d_in, const int* in_sizes, int n_in,
                              void* d_out, int out_size, void* d_ws, size_t ws_size,
                              hipStream_t stream) {
  const int* x_idx = (const int*)d_in[0];
  const int* eidx  = (const int*)d_in[1];
  const float* emb = (const float*)d_in[2];
  const float* W1  = (const float*)d_in[3];
  const float* b1  = (const float*)d_in[4];
  const float* W2  = (const float*)d_in[5];
  const float* b2  = (const float*)d_in[6];
  float* outp = (float*)d_out;

  int n = in_sizes[0];
  int E = in_sizes[1] / 2;
  const int* src = eidx;
  const int* dst = eidx + E;
  int B = (n + 127) >> BSH;     // dst-buckets (782 for n=100000, <=1024)

  char* w = (char*)d_ws;
  auto carve = [&](size_t bytes) {
    void* p = (void*)w;
    w += (bytes + 15) & ~size_t(15);
    return p;
  };
  int*   bcnt  = (int*)carve((size_t)B * CPAD * 4);
  int*   bfill = (int*)carve((size_t)B * CPAD * 4);
  int*   boff  = (int*)carve((size_t)B * 4);
  int*   ebuf  = (int*)carve((size_t)E * 4);
  int*   indeg = (int*)carve((size_t)n * 4);
  int*   rp    = (int*)carve((size_t)n * 4);
  float* dinv  = (float*)carve((size_t)n * 4);
  int*   partials = (int*)carve(512 * 4);
  int*   csr   = (int*)carve((size_t)E * 4);
  float* buf1  = (float*)carve((size_t)n * D * 4);
  float* buf2  = (float*)carve((size_t)n * D * 4);

  int nb = (n + 255) / 256;             // 391 <= 512
  int eb = (E + 255) / 256;

  k_zero<<<(B * CPAD + 255) / 256, 256, 0, stream>>>(bcnt, B * CPAD);
  k_bcount<<<eb, 256, 0, stream>>>(dst, bcnt, E);
  k_bscan<<<1, 1024, 0, stream>>>(bcnt, boff, bfill, B);
  k_bscatter<<<eb, 256, 0, stream>>>(src, dst, bfill, ebuf, E);
  k_bdeg<<<B, 256, 0, stream>>>(ebuf, boff, bcnt, indeg, n);
  k_scan1<<<nb, 256, 0, stream>>>(indeg, rp, partials, n);
  k_scan2<<<1, 512, 0, stream>>>(partials, nb);
  k_scan3<<<nb, 256, 0, stream>>>(indeg, rp, partials, dinv, n);
  k_bfill<<<B, 256, 0, stream>>>(ebuf, boff, bcnt, rp, csr, n);

  dim3 gemm_grid((n + 63) / 64, D / 64);
  int agg_blocks = (n * 32 + 255) / 256;

  k_gemm<<<gemm_grid, 256, 0, stream>>>(emb, x_idx, W1, dinv, buf1, n);
  k_agg<<<agg_blocks, 256, 0, stream>>>(buf1, rp, indeg, csr, dinv, b1, buf2, n, 1);
  k_gemm<<<gemm_grid, 256, 0, stream>>>(buf2, nullptr, W2, dinv, buf1, n);
  k_agg<<<agg_blocks, 256, 0, stream>>>(buf1, rp, indeg, csr, dinv, b2, outp, n, 0);
}

// Round 7
// 618.287 us; speedup vs baseline: 1.2289x; 1.2289x over previous
//
#include <hip/hip_runtime.h>
#include <hip/hip_fp16.h>

#define D 128
#define BSH 7              // nodes per bucket = 128
#define CPAD 16            // pad bucket counters to 1 per 64B line

// ---------------- preprocessing: bucketed CSR build ----------------
// Assumes n <= 131072 (bucket count <= 1024) and src/dst < 2^17.

__global__ void k_zero(int* __restrict__ p, int n) {
  int i = blockIdx.x * 256 + threadIdx.x;
  if (i < n) p[i] = 0;
}

// count edges per dst-bucket (padded counters)
__global__ void k_bcount(const int* __restrict__ dst, int* __restrict__ bcnt, int E) {
  int e = blockIdx.x * 256 + threadIdx.x;
  if (e < E) atomicAdd(&bcnt[(dst[e] >> BSH) * CPAD], 1);
}

// single-block exclusive scan over B buckets (B <= 1024); init bfill = boff
__global__ void k_bscan(const int* __restrict__ bcnt, int* __restrict__ boff,
                        int* __restrict__ bfill, int B) {
  __shared__ int s[1024];
  int t = threadIdx.x;
  int v = (t < B) ? bcnt[t * CPAD] : 0;
  s[t] = v;
  __syncthreads();
  for (int off = 1; off < 1024; off <<= 1) {
    int x = (t >= off) ? s[t - off] : 0;
    __syncthreads();
    s[t] += x;
    __syncthreads();
  }
  if (t < B) {
    int e = s[t] - v;
    boff[t] = e;
    bfill[t * CPAD] = e;
  }
}

// scatter edges into bucket-contiguous storage, packed (src<<7)|(dst&127)
__global__ void k_bscatter(const int* __restrict__ src, const int* __restrict__ dst,
                           int* __restrict__ bfill, int* __restrict__ ebuf, int E) {
  int e = blockIdx.x * 256 + threadIdx.x;
  if (e < E) {
    int d = dst[e];
    int pos = atomicAdd(&bfill[(d >> BSH) * CPAD], 1);
    ebuf[pos] = (src[e] << BSH) | (d & 127);
  }
}

// per-bucket degree count via LDS atomics; coalesced indeg write
__global__ __launch_bounds__(256) void k_bdeg(const int* __restrict__ ebuf,
                                              const int* __restrict__ boff,
                                              const int* __restrict__ bcnt,
                                              int* __restrict__ indeg, int n) {
  __shared__ int cnt[128];
  int b = blockIdx.x, t = threadIdx.x;
  if (t < 128) cnt[t] = 0;
  __syncthreads();
  int s0 = boff[b], m = bcnt[b * CPAD];
  for (int i = t; i < m; i += 256) atomicAdd(&cnt[ebuf[s0 + i] & 127], 1);
  __syncthreads();
  int node = (b << BSH) + t;
  if (t < 128 && node < n) indeg[node] = cnt[t];
}

// block-level exclusive scan (256/block) over indeg
__global__ void k_scan1(const int* __restrict__ indeg, int* __restrict__ rp,
                        int* __restrict__ partials, int n) {
  __shared__ int s[256];
  int t = threadIdx.x;
  int i = blockIdx.x * 256 + t;
  int v = (i < n) ? indeg[i] : 0;
  s[t] = v;
  __syncthreads();
  for (int off = 1; off < 256; off <<= 1) {
    int x = (t >= off) ? s[t - off] : 0;
    __syncthreads();
    s[t] += x;
    __syncthreads();
  }
  if (i < n) rp[i] = s[t] - v;
  if (t == 255) partials[blockIdx.x] = s[255];
}

__global__ void k_scan2(int* __restrict__ partials, int nb) {
  __shared__ int s[512];
  int t = threadIdx.x;
  int v = (t < nb) ? partials[t] : 0;
  s[t] = v;
  __syncthreads();
  for (int off = 1; off < 512; off <<= 1) {
    int x = (t >= off) ? s[t - off] : 0;
    __syncthreads();
    s[t] += x;
    __syncthreads();
  }
  if (t < nb) partials[t] = s[t] - v;
}

__global__ void k_scan3(const int* __restrict__ indeg, int* __restrict__ rp,
                        const int* __restrict__ partials, float* __restrict__ dinv, int n) {
  int i = blockIdx.x * 256 + threadIdx.x;
  if (i < n) {
    rp[i] = rp[i] + partials[blockIdx.x];
    dinv[i] = rsqrtf((float)(indeg[i] + 1));
  }
}

// per-bucket CSR fill: LDS local fill counters + rp staged in LDS;
// csr writes confined to the bucket's contiguous range (lines written once)
__global__ __launch_bounds__(256) void k_bfill(const int* __restrict__ ebuf,
                                               const int* __restrict__ boff,
                                               const int* __restrict__ bcnt,
                                               const int* __restrict__ rp,
                                               int* __restrict__ csr, int n) {
  __shared__ int lc[128];
  __shared__ int lrp[128];
  int b = blockIdx.x, t = threadIdx.x;
  int base = b << BSH;
  if (t < 128) {
    lc[t] = 0;
    int node = base + t;
    lrp[t] = (node < n) ? rp[node] : 0;
  }
  __syncthreads();
  int s0 = boff[b], m = bcnt[b * CPAD];
  for (int i = t; i < m; i += 256) {
    int p = ebuf[s0 + i];
    int ln = p & 127;
    int l = atomicAdd(&lc[ln], 1);
    csr[lrp[ln] + l] = p >> BSH;
  }
}

// ---------------- GEMM: out[row] = fp16( dinv[row] * (X[gather(row)] @ W) ) ------

#define F4E(v, j) ((j) == 0 ? (v).x : ((j) == 1 ? (v).y : ((j) == 2 ? (v).z : (v).w)))

__global__ __launch_bounds__(256) void k_gemm(const float* __restrict__ X,
                                              const int* __restrict__ xidx,
                                              const float* __restrict__ W,
                                              const float* __restrict__ dinv,
                                              __half* __restrict__ out, int n) {
  __shared__ float Xs[64 * D];   // 32 KB
  __shared__ float Ws[D * 64];   // 32 KB
  int tid = threadIdx.x;
  int r0 = blockIdx.x * 64;
  int c0 = blockIdx.y * 64;

  {
    const float4* W4 = (const float4*)W;
    float4* Ws4 = (float4*)Ws;
    for (int i = tid; i < 128 * 16; i += 256) {
      int k = i >> 4, cc = i & 15;
      Ws4[i] = W4[k * (D / 4) + (c0 >> 2) + cc];
    }
  }
  {
    float4* Xs4 = (float4*)Xs;
    const float4* X4 = (const float4*)X;
    for (int i = tid; i < 64 * 32; i += 256) {
      int r = i >> 5, kc = i & 31;
      int row = r0 + r;
      float4 v = make_float4(0.f, 0.f, 0.f, 0.f);
      if (row < n) {
        int srow = xidx ? xidx[row] : row;
        v = X4[srow * 32 + kc];
      }
      Xs4[i] = v;
    }
  }
  __syncthreads();

  int cg = (tid & 15) * 4;
  int rg = (tid >> 4) * 4;
  float acc[4][4] = {{0.f}};
  const float4* Xs4 = (const float4*)Xs;
  const float4* Ws4 = (const float4*)Ws;

#pragma unroll 4
  for (int k4 = 0; k4 < D; k4 += 4) {
    float4 a[4], w[4];
#pragma unroll
    for (int i = 0; i < 4; i++) a[i] = Xs4[((rg + i) * D + k4) >> 2];
#pragma unroll
    for (int kk = 0; kk < 4; kk++) w[kk] = Ws4[((k4 + kk) * 64 + cg) >> 2];
#pragma unroll
    for (int kk = 0; kk < 4; kk++)
#pragma unroll
      for (int i = 0; i < 4; i++)
#pragma unroll
        for (int j = 0; j < 4; j++)
          acc[i][j] += F4E(a[i], kk) * F4E(w[kk], j);
  }

#pragma unroll
  for (int i = 0; i < 4; i++) {
    int row = r0 + rg + i;
    if (row < n) {
      float sc = dinv[row];
      __half2 p0 = __floats2half2_rn(acc[i][0] * sc, acc[i][1] * sc);
      __half2 p1 = __floats2half2_rn(acc[i][2] * sc, acc[i][3] * sc);
      uint2 o;
      o.x = *(unsigned int*)&p0;
      o.y = *(unsigned int*)&p1;
      ((uint2*)out)[row * 32 + ((c0 + cg) >> 2)] = o;
    }
  }
}

// ---------------- aggregation ----------------
// out[d] = act(dinv[d]*(sum_{s->d} hs[s] + hs[d]) + b); 32-lane group per node,
// lane owns 4 cols = one uint2 (4 halves). fp32 accumulation. 8x unroll.

__device__ __forceinline__ void acc_h4(float4& acc, uint2 u) {
  __half2 h0 = *(__half2*)&u.x;
  __half2 h1 = *(__half2*)&u.y;
  float2 f0 = __half22float2(h0);
  float2 f1 = __half22float2(h1);
  acc.x += f0.x; acc.y += f0.y; acc.z += f1.x; acc.w += f1.y;
}

__global__ __launch_bounds__(256) void k_agg(const __half* __restrict__ hs,
                                             const int* __restrict__ rp,
                                             const int* __restrict__ indeg,
                                             const int* __restrict__ csr,
                                             const float* __restrict__ dinv,
                                             const float* __restrict__ bias,
                                             float* __restrict__ out, int n, int relu) {
  int lane = threadIdx.x & 31;
  int d = (blockIdx.x * 256 + threadIdx.x) >> 5;
  if (d >= n) return;
  const uint2* hsu = (const uint2*)hs;
  float4 acc = make_float4(0.f, 0.f, 0.f, 0.f);
  acc_h4(acc, hsu[d * 32 + lane]);      // self-loop term (hs = dinv*h)
  int start = rp[d];
  int cnt = indeg[d];
  const int* nb = csr + start;

  int e = 0;
  for (; e + 8 <= cnt; e += 8) {
    int s0 = nb[e],     s1 = nb[e + 1], s2 = nb[e + 2], s3 = nb[e + 3];
    int s4 = nb[e + 4], s5 = nb[e + 5], s6 = nb[e + 6], s7 = nb[e + 7];
    uint2 u0 = hsu[s0 * 32 + lane];
    uint2 u1 = hsu[s1 * 32 + lane];
    uint2 u2 = hsu[s2 * 32 + lane];
    uint2 u3 = hsu[s3 * 32 + lane];
    uint2 u4 = hsu[s4 * 32 + lane];
    uint2 u5 = hsu[s5 * 32 + lane];
    uint2 u6 = hsu[s6 * 32 + lane];
    uint2 u7 = hsu[s7 * 32 + lane];
    acc_h4(acc, u0); acc_h4(acc, u1); acc_h4(acc, u2); acc_h4(acc, u3);
    acc_h4(acc, u4); acc_h4(acc, u5); acc_h4(acc, u6); acc_h4(acc, u7);
  }
  for (; e + 4 <= cnt; e += 4) {
    int s0 = nb[e], s1 = nb[e + 1], s2 = nb[e + 2], s3 = nb[e + 3];
    uint2 u0 = hsu[s0 * 32 + lane];
    uint2 u1 = hsu[s1 * 32 + lane];
    uint2 u2 = hsu[s2 * 32 + lane];
    uint2 u3 = hsu[s3 * 32 + lane];
    acc_h4(acc, u0); acc_h4(acc, u1); acc_h4(acc, u2); acc_h4(acc, u3);
  }
  for (; e < cnt; e++) acc_h4(acc, hsu[nb[e] * 32 + lane]);

  float sc = dinv[d];
  float4 bv = ((const float4*)bias)[lane];
  float4 o;
  o.x = sc * acc.x + bv.x;
  o.y = sc * acc.y + bv.y;
  o.z = sc * acc.z + bv.z;
  o.w = sc * acc.w + bv.w;
  if (relu) {
    o.x = fmaxf(o.x, 0.f); o.y = fmaxf(o.y, 0.f);
    o.z = fmaxf(o.z, 0.f); o.w = fmaxf(o.w, 0.f);
  }
  ((float4*)out)[d * 32 + lane] = o;
}

// ---------------- launcher ----------------

extern "C" void kernel_launch(void* const* d_in, const int* in_sizes, int n_in,
                              void* d_out, int out_size, void* d_ws, size_t ws_size,
                              hipStream_t stream) {
  const int* x_idx = (const int*)d_in[0];
  const int* eidx  = (const int*)d_in[1];
  const float* emb = (const float*)d_in[2];
  const float* W1  = (const float*)d_in[3];
  const float* b1  = (const float*)d_in[4];
  const float* W2  = (const float*)d_in[5];
  const float* b2  = (const float*)d_in[6];
  float* outp = (float*)d_out;

  int n = in_sizes[0];
  int E = in_sizes[1] / 2;
  const int* src = eidx;
  const int* dst = eidx + E;
  int B = (n + 127) >> BSH;     // dst-buckets (782 for n=100000, <=1024)

  char* w = (char*)d_ws;
  auto carve = [&](size_t bytes) {
    void* p = (void*)w;
    w += (bytes + 15) & ~size_t(15);
    return p;
  };
  int*    bcnt  = (int*)carve((size_t)B * CPAD * 4);
  int*    bfill = (int*)carve((size_t)B * CPAD * 4);
  int*    boff  = (int*)carve((size_t)B * 4);
  int*    ebuf  = (int*)carve((size_t)E * 4);
  int*    indeg = (int*)carve((size_t)n * 4);
  int*    rp    = (int*)carve((size_t)n * 4);
  float*  dinv  = (float*)carve((size_t)n * 4);
  int*    partials = (int*)carve(512 * 4);
  int*    csr   = (int*)carve((size_t)E * 4);
  __half* hbuf  = (__half*)carve((size_t)n * D * 2);   // fp16 message buffer (both layers)
  float*  buf2  = (float*)carve((size_t)n * D * 4);    // fp32 layer-1 output

  int nb = (n + 255) / 256;             // 391 <= 512
  int eb = (E + 255) / 256;

  k_zero<<<(B * CPAD + 255) / 256, 256, 0, stream>>>(bcnt, B * CPAD);
  k_bcount<<<eb, 256, 0, stream>>>(dst, bcnt, E);
  k_bscan<<<1, 1024, 0, stream>>>(bcnt, boff, bfill, B);
  k_bscatter<<<eb, 256, 0, stream>>>(src, dst, bfill, ebuf, E);
  k_bdeg<<<B, 256, 0, stream>>>(ebuf, boff, bcnt, indeg, n);
  k_scan1<<<nb, 256, 0, stream>>>(indeg, rp, partials, n);
  k_scan2<<<1, 512, 0, stream>>>(partials, nb);
  k_scan3<<<nb, 256, 0, stream>>>(indeg, rp, partials, dinv, n);
  k_bfill<<<B, 256, 0, stream>>>(ebuf, boff, bcnt, rp, csr, n);

  dim3 gemm_grid((n + 63) / 64, D / 64);
  int agg_blocks = (n * 32 + 255) / 256;

  k_gemm<<<gemm_grid, 256, 0, stream>>>(emb, x_idx, W1, dinv, hbuf, n);
  k_agg<<<agg_blocks, 256, 0, stream>>>(hbuf, rp, indeg, csr, dinv, b1, buf2, n, 1);
  k_gemm<<<gemm_grid, 256, 0, stream>>>(buf2, nullptr, W2, dinv, hbuf, n);
  k_agg<<<agg_blocks, 256, 0, stream>>>(hbuf, rp, indeg, csr, dinv, b2, outp, n, 0);
}

// Round 8
// 506.578 us; speedup vs baseline: 1.4999x; 1.2205x over previous
//
#include <hip/hip_runtime.h>
#include <hip/hip_fp16.h>

#define D 128
#define BSH 7              // nodes per bucket = 128
#define CPAD 16            // pad bucket counters to 1 per 64B line
#define WS_P 144           // LDS row stride (f16) for W tile: 16B-aligned rows,
                           // bank = (8m+2b)%32 -> perfect 4-deep spread for b64 reads

typedef _Float16 f16x4 __attribute__((ext_vector_type(4)));
typedef float f32x4 __attribute__((ext_vector_type(4)));

// ---------------- preprocessing: bucketed CSR build ----------------

__global__ void k_zero(int* __restrict__ p, int n) {
  int i = blockIdx.x * 256 + threadIdx.x;
  if (i < n) p[i] = 0;
}

__global__ void k_bcount(const int* __restrict__ dst, int* __restrict__ bcnt, int E) {
  int e = blockIdx.x * 256 + threadIdx.x;
  if (e < E) atomicAdd(&bcnt[(dst[e] >> BSH) * CPAD], 1);
}

__global__ void k_bscan(const int* __restrict__ bcnt, int* __restrict__ boff,
                        int* __restrict__ bfill, int B) {
  __shared__ int s[1024];
  int t = threadIdx.x;
  int v = (t < B) ? bcnt[t * CPAD] : 0;
  s[t] = v;
  __syncthreads();
  for (int off = 1; off < 1024; off <<= 1) {
    int x = (t >= off) ? s[t - off] : 0;
    __syncthreads();
    s[t] += x;
    __syncthreads();
  }
  if (t < B) {
    int e = s[t] - v;
    boff[t] = e;
    bfill[t * CPAD] = e;
  }
}

__global__ void k_bscatter(const int* __restrict__ src, const int* __restrict__ dst,
                           int* __restrict__ bfill, int* __restrict__ ebuf, int E) {
  int e = blockIdx.x * 256 + threadIdx.x;
  if (e < E) {
    int d = dst[e];
    int pos = atomicAdd(&bfill[(d >> BSH) * CPAD], 1);
    ebuf[pos] = (src[e] << BSH) | (d & 127);
  }
}

__global__ __launch_bounds__(256) void k_bdeg(const int* __restrict__ ebuf,
                                              const int* __restrict__ boff,
                                              const int* __restrict__ bcnt,
                                              int* __restrict__ indeg, int n) {
  __shared__ int cnt[128];
  int b = blockIdx.x, t = threadIdx.x;
  if (t < 128) cnt[t] = 0;
  __syncthreads();
  int s0 = boff[b], m = bcnt[b * CPAD];
  for (int i = t; i < m; i += 256) atomicAdd(&cnt[ebuf[s0 + i] & 127], 1);
  __syncthreads();
  int node = (b << BSH) + t;
  if (t < 128 && node < n) indeg[node] = cnt[t];
}

__global__ void k_scan1(const int* __restrict__ indeg, int* __restrict__ rp,
                        int* __restrict__ partials, int n) {
  __shared__ int s[256];
  int t = threadIdx.x;
  int i = blockIdx.x * 256 + t;
  int v = (i < n) ? indeg[i] : 0;
  s[t] = v;
  __syncthreads();
  for (int off = 1; off < 256; off <<= 1) {
    int x = (t >= off) ? s[t - off] : 0;
    __syncthreads();
    s[t] += x;
    __syncthreads();
  }
  if (i < n) rp[i] = s[t] - v;
  if (t == 255) partials[blockIdx.x] = s[255];
}

__global__ void k_scan2(int* __restrict__ partials, int nb) {
  __shared__ int s[512];
  int t = threadIdx.x;
  int v = (t < nb) ? partials[t] : 0;
  s[t] = v;
  __syncthreads();
  for (int off = 1; off < 512; off <<= 1) {
    int x = (t >= off) ? s[t - off] : 0;
    __syncthreads();
    s[t] += x;
    __syncthreads();
  }
  if (t < nb) partials[t] = s[t] - v;
}

__global__ void k_scan3(const int* __restrict__ indeg, int* __restrict__ rp,
                        const int* __restrict__ partials, float* __restrict__ dinv, int n) {
  int i = blockIdx.x * 256 + threadIdx.x;
  if (i < n) {
    rp[i] = rp[i] + partials[blockIdx.x];
    dinv[i] = rsqrtf((float)(indeg[i] + 1));
  }
}

__global__ __launch_bounds__(256) void k_bfill(const int* __restrict__ ebuf,
                                               const int* __restrict__ boff,
                                               const int* __restrict__ bcnt,
                                               const int* __restrict__ rp,
                                               int* __restrict__ csr, int n) {
  __shared__ int lc[128];
  __shared__ int lrp[128];
  int b = blockIdx.x, t = threadIdx.x;
  int base = b << BSH;
  if (t < 128) {
    lc[t] = 0;
    int node = base + t;
    lrp[t] = (node < n) ? rp[node] : 0;
  }
  __syncthreads();
  int s0 = boff[b], m = bcnt[b * CPAD];
  for (int i = t; i < m; i += 256) {
    int p = ebuf[s0 + i];
    int ln = p & 127;
    int l = atomicAdd(&lc[ln], 1);
    csr[lrp[ln] + l] = p >> BSH;
  }
}

// ---------------- W convert: Wt[n][k] = fp16(W[k][n]) ----------------

__global__ void k_wconv(const float* __restrict__ W, __half* __restrict__ Wt) {
  int idx = blockIdx.x * 256 + threadIdx.x;   // 16384 threads
  int nn = idx >> 7, k = idx & 127;
  Wt[idx] = __float2half(W[k * 128 + nn]);
}

// ---------------- MFMA GEMM: out16[row] = fp16( dinv[row] * (X[g(row)] @ W) ) ----
// 16x16x16_f16 MFMA. Block = 256 thr = 4 waves; wave owns 16 rows x 128 cols.
// A direct from global (64B contiguous per 16-lane group per k-step);
// B (=Wt) staged in LDS with WS_P-padded rows (conflict-free b64 reads).

template<int XMODE>   // 0: fp32 X + gather; 1: fp16 X
__global__ __launch_bounds__(256) void k_mgemm(const void* __restrict__ Xv,
                                               const int* __restrict__ xidx,
                                               const __half* __restrict__ Wt,
                                               const float* __restrict__ dinv,
                                               __half* __restrict__ out, int n) {
  __shared__ __half Ws[128 * WS_P];   // 36 KB
  int tid = threadIdx.x;
  {
    const uint4* Wt4 = (const uint4*)Wt;
    for (int i = tid; i < 128 * 16; i += 256) {
      int row = i >> 4, c8 = i & 15;
      *(uint4*)&Ws[row * WS_P + c8 * 8] = Wt4[i];
    }
  }
  __syncthreads();

  int wave = tid >> 6, lane = tid & 63;
  int m = lane & 15, b = lane >> 4;
  int r0 = blockIdx.x * 64 + wave * 16;
  int rowA = r0 + m; if (rowA > n - 1) rowA = n - 1;
  int srow = (XMODE == 0 && xidx) ? xidx[rowA] : rowA;

  f32x4 acc[8];
#pragma unroll
  for (int t = 0; t < 8; t++) acc[t] = (f32x4){0.f, 0.f, 0.f, 0.f};

#pragma unroll
  for (int ks = 0; ks < 8; ks++) {
    f16x4 a;
    if (XMODE == 0) {
      float4 ax = ((const float4*)Xv)[srow * 32 + ks * 4 + b];
      a[0] = (_Float16)ax.x; a[1] = (_Float16)ax.y;
      a[2] = (_Float16)ax.z; a[3] = (_Float16)ax.w;
    } else {
      uint2 ux = ((const uint2*)Xv)[srow * 32 + ks * 4 + b];
      a = *(f16x4*)&ux;
    }
    int kb = ks * 16 + 4 * b;
#pragma unroll
    for (int nt = 0; nt < 8; nt++) {
      f16x4 bb = *(const f16x4*)&Ws[(nt * 16 + m) * WS_P + kb];
      acc[nt] = __builtin_amdgcn_mfma_f32_16x16x16f16(a, bb, acc[nt], 0, 0, 0);
    }
  }

  // D: lane holds D[4b+i][nt*16+m]
  int rs0 = r0 + 4 * b;
  float dv[4];
#pragma unroll
  for (int i = 0; i < 4; i++) {
    int r = rs0 + i;
    dv[i] = dinv[r > n - 1 ? n - 1 : r];
  }
#pragma unroll
  for (int nt = 0; nt < 8; nt++) {
#pragma unroll
    for (int i = 0; i < 4; i++) {
      int r = rs0 + i;
      if (r < n) out[(size_t)r * 128 + nt * 16 + m] = __float2half(acc[nt][i] * dv[i]);
    }
  }
}

// ---------------- aggregation ----------------
// out[d] = act(dinv[d]*(sum_{s->d} hs[s] + hs[d]) + b); 32-lane group per node,
// lane owns 4 cols = one uint2 (4 halves). fp32 accumulation. 8x unroll.
// out16=1 -> fp16 output (feeds next GEMM), else fp32.

__device__ __forceinline__ void acc_h4(float4& acc, uint2 u) {
  __half2 h0 = *(__half2*)&u.x;
  __half2 h1 = *(__half2*)&u.y;
  float2 f0 = __half22float2(h0);
  float2 f1 = __half22float2(h1);
  acc.x += f0.x; acc.y += f0.y; acc.z += f1.x; acc.w += f1.y;
}

__global__ __launch_bounds__(256) void k_agg(const __half* __restrict__ hs,
                                             const int* __restrict__ rp,
                                             const int* __restrict__ indeg,
                                             const int* __restrict__ csr,
                                             const float* __restrict__ dinv,
                                             const float* __restrict__ bias,
                                             void* __restrict__ outv, int n,
                                             int relu, int out16) {
  int lane = threadIdx.x & 31;
  int d = (blockIdx.x * 256 + threadIdx.x) >> 5;
  if (d >= n) return;
  const uint2* hsu = (const uint2*)hs;
  float4 acc = make_float4(0.f, 0.f, 0.f, 0.f);
  acc_h4(acc, hsu[d * 32 + lane]);      // self-loop term (hs = dinv*h)
  int start = rp[d];
  int cnt = indeg[d];
  const int* nb = csr + start;

  int e = 0;
  for (; e + 8 <= cnt; e += 8) {
    int s0 = nb[e],     s1 = nb[e + 1], s2 = nb[e + 2], s3 = nb[e + 3];
    int s4 = nb[e + 4], s5 = nb[e + 5], s6 = nb[e + 6], s7 = nb[e + 7];
    uint2 u0 = hsu[s0 * 32 + lane];
    uint2 u1 = hsu[s1 * 32 + lane];
    uint2 u2 = hsu[s2 * 32 + lane];
    uint2 u3 = hsu[s3 * 32 + lane];
    uint2 u4 = hsu[s4 * 32 + lane];
    uint2 u5 = hsu[s5 * 32 + lane];
    uint2 u6 = hsu[s6 * 32 + lane];
    uint2 u7 = hsu[s7 * 32 + lane];
    acc_h4(acc, u0); acc_h4(acc, u1); acc_h4(acc, u2); acc_h4(acc, u3);
    acc_h4(acc, u4); acc_h4(acc, u5); acc_h4(acc, u6); acc_h4(acc, u7);
  }
  for (; e + 4 <= cnt; e += 4) {
    int s0 = nb[e], s1 = nb[e + 1], s2 = nb[e + 2], s3 = nb[e + 3];
    uint2 u0 = hsu[s0 * 32 + lane];
    uint2 u1 = hsu[s1 * 32 + lane];
    uint2 u2 = hsu[s2 * 32 + lane];
    uint2 u3 = hsu[s3 * 32 + lane];
    acc_h4(acc, u0); acc_h4(acc, u1); acc_h4(acc, u2); acc_h4(acc, u3);
  }
  for (; e < cnt; e++) acc_h4(acc, hsu[nb[e] * 32 + lane]);

  float sc = dinv[d];
  float4 bv = ((const float4*)bias)[lane];
  float4 o;
  o.x = sc * acc.x + bv.x;
  o.y = sc * acc.y + bv.y;
  o.z = sc * acc.z + bv.z;
  o.w = sc * acc.w + bv.w;
  if (relu) {
    o.x = fmaxf(o.x, 0.f); o.y = fmaxf(o.y, 0.f);
    o.z = fmaxf(o.z, 0.f); o.w = fmaxf(o.w, 0.f);
  }
  if (out16) {
    __half2 p0 = __floats2half2_rn(o.x, o.y);
    __half2 p1 = __floats2half2_rn(o.z, o.w);
    uint2 u;
    u.x = *(unsigned int*)&p0;
    u.y = *(unsigned int*)&p1;
    ((uint2*)outv)[d * 32 + lane] = u;
  } else {
    ((float4*)outv)[d * 32 + lane] = o;
  }
}

// ---------------- launcher ----------------

extern "C" void kernel_launch(void* const* d_in, const int* in_sizes, int n_in,
                              void* d_out, int out_size, void* d_ws, size_t ws_size,
                              hipStream_t stream) {
  const int* x_idx = (const int*)d_in[0];
  const int* eidx  = (const int*)d_in[1];
  const float* emb = (const float*)d_in[2];
  const float* W1  = (const float*)d_in[3];
  const float* b1  = (const float*)d_in[4];
  const float* W2  = (const float*)d_in[5];
  const float* b2  = (const float*)d_in[6];
  float* outp = (float*)d_out;

  int n = in_sizes[0];
  int E = in_sizes[1] / 2;
  const int* src = eidx;
  const int* dst = eidx + E;
  int B = (n + 127) >> BSH;     // 782 <= 1024

  char* w = (char*)d_ws;
  auto carve = [&](size_t bytes) {
    void* p = (void*)w;
    w += (bytes + 15) & ~size_t(15);
    return p;
  };
  int*    bcnt  = (int*)carve((size_t)B * CPAD * 4);
  int*    bfill = (int*)carve((size_t)B * CPAD * 4);
  int*    boff  = (int*)carve((size_t)B * 4);
  int*    ebuf  = (int*)carve((size_t)E * 4);
  int*    indeg = (int*)carve((size_t)n * 4);
  int*    rp    = (int*)carve((size_t)n * 4);
  float*  dinv  = (float*)carve((size_t)n * 4);
  int*    partials = (int*)carve(512 * 4);
  int*    csr   = (int*)carve((size_t)E * 4);
  __half* Wt1   = (__half*)carve(128 * 128 * 2);
  __half* Wt2   = (__half*)carve(128 * 128 * 2);
  __half* h16   = (__half*)carve((size_t)n * D * 2);   // message buffer
  __half* x16   = (__half*)carve((size_t)n * D * 2);   // layer-1 activation

  int nb = (n + 255) / 256;
  int eb = (E + 255) / 256;

  k_zero<<<(B * CPAD + 255) / 256, 256, 0, stream>>>(bcnt, B * CPAD);
  k_bcount<<<eb, 256, 0, stream>>>(dst, bcnt, E);
  k_bscan<<<1, 1024, 0, stream>>>(bcnt, boff, bfill, B);
  k_bscatter<<<eb, 256, 0, stream>>>(src, dst, bfill, ebuf, E);
  k_bdeg<<<B, 256, 0, stream>>>(ebuf, boff, bcnt, indeg, n);
  k_scan1<<<nb, 256, 0, stream>>>(indeg, rp, partials, n);
  k_scan2<<<1, 512, 0, stream>>>(partials, nb);
  k_scan3<<<nb, 256, 0, stream>>>(indeg, rp, partials, dinv, n);
  k_bfill<<<B, 256, 0, stream>>>(ebuf, boff, bcnt, rp, csr, n);
  k_wconv<<<64, 256, 0, stream>>>(W1, Wt1);
  k_wconv<<<64, 256, 0, stream>>>(W2, Wt2);

  int gemm_blocks = (n + 63) / 64;
  int agg_blocks = (n * 32 + 255) / 256;

  k_mgemm<0><<<gemm_blocks, 256, 0, stream>>>(emb, x_idx, Wt1, dinv, h16, n);
  k_agg<<<agg_blocks, 256, 0, stream>>>(h16, rp, indeg, csr, dinv, b1, x16, n, 1, 1);
  k_mgemm<1><<<gemm_blocks, 256, 0, stream>>>(x16, nullptr, Wt2, dinv, h16, n);
  k_agg<<<agg_blocks, 256, 0, stream>>>(h16, rp, indeg, csr, dinv, b2, outp, n, 0, 0);
}

// Round 9
// 492.154 us; speedup vs baseline: 1.5439x; 1.0293x over previous
//
#include <hip/hip_runtime.h>
#include <hip/hip_fp16.h>

#define D 128
#define BSH 7              // nodes per bucket = 128
#define CPAD 16            // pad bucket counters to 1 per 64B line
#define NBMAX 1024
#define SCHUNK 16384       // edges per block in k_bscatter
#define WS_P 144           // LDS row stride (f16) for W tile (conflict-free b64 reads)

typedef _Float16 f16x4 __attribute__((ext_vector_type(4)));
typedef float f32x4 __attribute__((ext_vector_type(4)));

// ---------------- preprocessing: bucketed CSR build ----------------

__global__ void k_zero(int* __restrict__ p, int n) {
  int i = blockIdx.x * 256 + threadIdx.x;
  if (i < n) p[i] = 0;
}

__global__ void k_bcount(const int* __restrict__ dst, int* __restrict__ bcnt, int E) {
  int e = blockIdx.x * 256 + threadIdx.x;
  if (e < E) atomicAdd(&bcnt[(dst[e] >> BSH) * CPAD], 1);
}

__global__ void k_bscan(const int* __restrict__ bcnt, int* __restrict__ boff,
                        int* __restrict__ bfill, int B) {
  __shared__ int s[1024];
  int t = threadIdx.x;
  int v = (t < B) ? bcnt[t * CPAD] : 0;
  s[t] = v;
  __syncthreads();
  for (int off = 1; off < 1024; off <<= 1) {
    int x = (t >= off) ? s[t - off] : 0;
    __syncthreads();
    s[t] += x;
    __syncthreads();
  }
  if (t < B) {
    int e = s[t] - v;
    boff[t] = e;
    bfill[t * CPAD] = e;
  }
}

// scatter edges into bucket-contiguous storage, packed (src<<7)|(dst&127).
// Block-aggregated reservation: one global atomic per (block,bucket) run ->
// each run written by a single CU/XCD; lines stay in that XCD's L2 and
// write back once (vs per-edge atomics: 16x write amplification).
__global__ __launch_bounds__(256) void k_bscatter(const int* __restrict__ src,
                                                  const int* __restrict__ dst,
                                                  int* __restrict__ bfill,
                                                  int* __restrict__ ebuf,
                                                  int E, int B) {
  __shared__ int cnt[NBMAX];
  __shared__ int rbase[NBMAX];
  int t = threadIdx.x;
  int e0 = blockIdx.x * SCHUNK;
  int e1 = e0 + SCHUNK; if (e1 > E) e1 = E;

  for (int b = t; b < B; b += 256) cnt[b] = 0;
  __syncthreads();
  for (int e = e0 + t; e < e1; e += 256) atomicAdd(&cnt[dst[e] >> BSH], 1);
  __syncthreads();
  for (int b = t; b < B; b += 256) {
    int c = cnt[b];
    rbase[b] = c ? atomicAdd(&bfill[b * CPAD], c) : 0;
  }
  __syncthreads();
  for (int b = t; b < B; b += 256) cnt[b] = 0;   // reuse as local cursor
  __syncthreads();
  for (int e = e0 + t; e < e1; e += 256) {
    int d = dst[e];
    int b = d >> BSH;
    int slot = atomicAdd(&cnt[b], 1);
    ebuf[rbase[b] + slot] = (src[e] << BSH) | (d & 127);
  }
}

__global__ __launch_bounds__(256) void k_bdeg(const int* __restrict__ ebuf,
                                              const int* __restrict__ boff,
                                              const int* __restrict__ bcnt,
                                              int* __restrict__ indeg, int n) {
  __shared__ int cnt[128];
  int b = blockIdx.x, t = threadIdx.x;
  if (t < 128) cnt[t] = 0;
  __syncthreads();
  int s0 = boff[b], m = bcnt[b * CPAD];
  for (int i = t; i < m; i += 256) atomicAdd(&cnt[ebuf[s0 + i] & 127], 1);
  __syncthreads();
  int node = (b << BSH) + t;
  if (t < 128 && node < n) indeg[node] = cnt[t];
}

__global__ void k_scan1(const int* __restrict__ indeg, int* __restrict__ rp,
                        int* __restrict__ partials, int n) {
  __shared__ int s[256];
  int t = threadIdx.x;
  int i = blockIdx.x * 256 + t;
  int v = (i < n) ? indeg[i] : 0;
  s[t] = v;
  __syncthreads();
  for (int off = 1; off < 256; off <<= 1) {
    int x = (t >= off) ? s[t - off] : 0;
    __syncthreads();
    s[t] += x;
    __syncthreads();
  }
  if (i < n) rp[i] = s[t] - v;
  if (t == 255) partials[blockIdx.x] = s[255];
}

__global__ void k_scan2(int* __restrict__ partials, int nb) {
  __shared__ int s[512];
  int t = threadIdx.x;
  int v = (t < nb) ? partials[t] : 0;
  s[t] = v;
  __syncthreads();
  for (int off = 1; off < 512; off <<= 1) {
    int x = (t >= off) ? s[t - off] : 0;
    __syncthreads();
    s[t] += x;
    __syncthreads();
  }
  if (t < nb) partials[t] = s[t] - v;
}

__global__ void k_scan3(const int* __restrict__ indeg, int* __restrict__ rp,
                        const int* __restrict__ partials, float* __restrict__ dinv, int n) {
  int i = blockIdx.x * 256 + threadIdx.x;
  if (i < n) {
    rp[i] = rp[i] + partials[blockIdx.x];
    dinv[i] = rsqrtf((float)(indeg[i] + 1));
  }
}

__global__ __launch_bounds__(256) void k_bfill(const int* __restrict__ ebuf,
                                               const int* __restrict__ boff,
                                               const int* __restrict__ bcnt,
                                               const int* __restrict__ rp,
                                               int* __restrict__ csr, int n) {
  __shared__ int lc[128];
  __shared__ int lrp[128];
  int b = blockIdx.x, t = threadIdx.x;
  int base = b << BSH;
  if (t < 128) {
    lc[t] = 0;
    int node = base + t;
    lrp[t] = (node < n) ? rp[node] : 0;
  }
  __syncthreads();
  int s0 = boff[b], m = bcnt[b * CPAD];
  for (int i = t; i < m; i += 256) {
    int p = ebuf[s0 + i];
    int ln = p & 127;
    int l = atomicAdd(&lc[ln], 1);
    csr[lrp[ln] + l] = p >> BSH;
  }
}

// ---------------- W convert: Wt[n][k] = fp16(W[k][n]) ----------------

__global__ void k_wconv(const float* __restrict__ W, __half* __restrict__ Wt) {
  int idx = blockIdx.x * 256 + threadIdx.x;   // 16384 threads
  int nn = idx >> 7, k = idx & 127;
  Wt[idx] = __float2half(W[k * 128 + nn]);
}

// ---------------- MFMA GEMM: out16[row] = fp16( dinv[row] * (X[g(row)] @ W) ) ----

template<int XMODE>   // 0: fp32 X + gather; 1: fp16 X
__global__ __launch_bounds__(256) void k_mgemm(const void* __restrict__ Xv,
                                               const int* __restrict__ xidx,
                                               const __half* __restrict__ Wt,
                                               const float* __restrict__ dinv,
                                               __half* __restrict__ out, int n) {
  __shared__ __half Ws[128 * WS_P];   // 36 KB
  int tid = threadIdx.x;
  {
    const uint4* Wt4 = (const uint4*)Wt;
    for (int i = tid; i < 128 * 16; i += 256) {
      int row = i >> 4, c8 = i & 15;
      *(uint4*)&Ws[row * WS_P + c8 * 8] = Wt4[i];
    }
  }
  __syncthreads();

  int wave = tid >> 6, lane = tid & 63;
  int m = lane & 15, b = lane >> 4;
  int r0 = blockIdx.x * 64 + wave * 16;
  int rowA = r0 + m; if (rowA > n - 1) rowA = n - 1;
  int srow = (XMODE == 0 && xidx) ? xidx[rowA] : rowA;

  f32x4 acc[8];
#pragma unroll
  for (int t = 0; t < 8; t++) acc[t] = (f32x4){0.f, 0.f, 0.f, 0.f};

#pragma unroll
  for (int ks = 0; ks < 8; ks++) {
    f16x4 a;
    if (XMODE == 0) {
      float4 ax = ((const float4*)Xv)[srow * 32 + ks * 4 + b];
      a[0] = (_Float16)ax.x; a[1] = (_Float16)ax.y;
      a[2] = (_Float16)ax.z; a[3] = (_Float16)ax.w;
    } else {
      uint2 ux = ((const uint2*)Xv)[srow * 32 + ks * 4 + b];
      a = *(f16x4*)&ux;
    }
    int kb = ks * 16 + 4 * b;
#pragma unroll
    for (int nt = 0; nt < 8; nt++) {
      f16x4 bb = *(const f16x4*)&Ws[(nt * 16 + m) * WS_P + kb];
      acc[nt] = __builtin_amdgcn_mfma_f32_16x16x16f16(a, bb, acc[nt], 0, 0, 0);
    }
  }

  // D: lane holds D[4b+i][nt*16+m]
  int rs0 = r0 + 4 * b;
  float dv[4];
#pragma unroll
  for (int i = 0; i < 4; i++) {
    int r = rs0 + i;
    dv[i] = dinv[r > n - 1 ? n - 1 : r];
  }
#pragma unroll
  for (int nt = 0; nt < 8; nt++) {
#pragma unroll
    for (int i = 0; i < 4; i++) {
      int r = rs0 + i;
      if (r < n) out[(size_t)r * 128 + nt * 16 + m] = __float2half(acc[nt][i] * dv[i]);
    }
  }
}

// ---------------- aggregation ----------------

__device__ __forceinline__ void acc_h4(float4& acc, uint2 u) {
  __half2 h0 = *(__half2*)&u.x;
  __half2 h1 = *(__half2*)&u.y;
  float2 f0 = __half22float2(h0);
  float2 f1 = __half22float2(h1);
  acc.x += f0.x; acc.y += f0.y; acc.z += f1.x; acc.w += f1.y;
}

__global__ __launch_bounds__(256) void k_agg(const __half* __restrict__ hs,
                                             const int* __restrict__ rp,
                                             const int* __restrict__ indeg,
                                             const int* __restrict__ csr,
                                             const float* __restrict__ dinv,
                                             const float* __restrict__ bias,
                                             void* __restrict__ outv, int n,
                                             int relu, int out16) {
  int lane = threadIdx.x & 31;
  int d = (blockIdx.x * 256 + threadIdx.x) >> 5;
  if (d >= n) return;
  const uint2* hsu = (const uint2*)hs;
  float4 acc = make_float4(0.f, 0.f, 0.f, 0.f);
  acc_h4(acc, hsu[d * 32 + lane]);      // self-loop term (hs = dinv*h)
  int start = rp[d];
  int cnt = indeg[d];
  const int* nb = csr + start;

  int e = 0;
  for (; e + 8 <= cnt; e += 8) {
    int s0 = nb[e],     s1 = nb[e + 1], s2 = nb[e + 2], s3 = nb[e + 3];
    int s4 = nb[e + 4], s5 = nb[e + 5], s6 = nb[e + 6], s7 = nb[e + 7];
    uint2 u0 = hsu[s0 * 32 + lane];
    uint2 u1 = hsu[s1 * 32 + lane];
    uint2 u2 = hsu[s2 * 32 + lane];
    uint2 u3 = hsu[s3 * 32 + lane];
    uint2 u4 = hsu[s4 * 32 + lane];
    uint2 u5 = hsu[s5 * 32 + lane];
    uint2 u6 = hsu[s6 * 32 + lane];
    uint2 u7 = hsu[s7 * 32 + lane];
    acc_h4(acc, u0); acc_h4(acc, u1); acc_h4(acc, u2); acc_h4(acc, u3);
    acc_h4(acc, u4); acc_h4(acc, u5); acc_h4(acc, u6); acc_h4(acc, u7);
  }
  for (; e + 4 <= cnt; e += 4) {
    int s0 = nb[e], s1 = nb[e + 1], s2 = nb[e + 2], s3 = nb[e + 3];
    uint2 u0 = hsu[s0 * 32 + lane];
    uint2 u1 = hsu[s1 * 32 + lane];
    uint2 u2 = hsu[s2 * 32 + lane];
    uint2 u3 = hsu[s3 * 32 + lane];
    acc_h4(acc, u0); acc_h4(acc, u1); acc_h4(acc, u2); acc_h4(acc, u3);
  }
  for (; e < cnt; e++) acc_h4(acc, hsu[nb[e] * 32 + lane]);

  float sc = dinv[d];
  float4 bv = ((const float4*)bias)[lane];
  float4 o;
  o.x = sc * acc.x + bv.x;
  o.y = sc * acc.y + bv.y;
  o.z = sc * acc.z + bv.z;
  o.w = sc * acc.w + bv.w;
  if (relu) {
    o.x = fmaxf(o.x, 0.f); o.y = fmaxf(o.y, 0.f);
    o.z = fmaxf(o.z, 0.f); o.w = fmaxf(o.w, 0.f);
  }
  if (out16) {
    __half2 p0 = __floats2half2_rn(o.x, o.y);
    __half2 p1 = __floats2half2_rn(o.z, o.w);
    uint2 u;
    u.x = *(unsigned int*)&p0;
    u.y = *(unsigned int*)&p1;
    ((uint2*)outv)[d * 32 + lane] = u;
  } else {
    ((float4*)outv)[d * 32 + lane] = o;
  }
}

// ---------------- launcher ----------------

extern "C" void kernel_launch(void* const* d_in, const int* in_sizes, int n_in,
                              void* d_out, int out_size, void* d_ws, size_t ws_size,
                              hipStream_t stream) {
  const int* x_idx = (const int*)d_in[0];
  const int* eidx  = (const int*)d_in[1];
  const float* emb = (const float*)d_in[2];
  const float* W1  = (const float*)d_in[3];
  const float* b1  = (const float*)d_in[4];
  const float* W2  = (const float*)d_in[5];
  const float* b2  = (const float*)d_in[6];
  float* outp = (float*)d_out;

  int n = in_sizes[0];
  int E = in_sizes[1] / 2;
  const int* src = eidx;
  const int* dst = eidx + E;
  int B = (n + 127) >> BSH;     // 782 <= 1024

  char* w = (char*)d_ws;
  auto carve = [&](size_t bytes) {
    void* p = (void*)w;
    w += (bytes + 15) & ~size_t(15);
    return p;
  };
  int*    bcnt  = (int*)carve((size_t)B * CPAD * 4);
  int*    bfill = (int*)carve((size_t)B * CPAD * 4);
  int*    boff  = (int*)carve((size_t)B * 4);
  int*    ebuf  = (int*)carve((size_t)E * 4);
  int*    indeg = (int*)carve((size_t)n * 4);
  int*    rp    = (int*)carve((size_t)n * 4);
  float*  dinv  = (float*)carve((size_t)n * 4);
  int*    partials = (int*)carve(512 * 4);
  int*    csr   = (int*)carve((size_t)E * 4);
  __half* Wt1   = (__half*)carve(128 * 128 * 2);
  __half* Wt2   = (__half*)carve(128 * 128 * 2);
  __half* h16   = (__half*)carve((size_t)n * D * 2);   // message buffer
  __half* x16   = (__half*)carve((size_t)n * D * 2);   // layer-1 activation

  int nb = (n + 255) / 256;
  int eb = (E + 255) / 256;
  int sb = (E + SCHUNK - 1) / SCHUNK;

  k_zero<<<(B * CPAD + 255) / 256, 256, 0, stream>>>(bcnt, B * CPAD);
  k_bcount<<<eb, 256, 0, stream>>>(dst, bcnt, E);
  k_bscan<<<1, 1024, 0, stream>>>(bcnt, boff, bfill, B);
  k_bscatter<<<sb, 256, 0, stream>>>(src, dst, bfill, ebuf, E, B);
  k_bdeg<<<B, 256, 0, stream>>>(ebuf, boff, bcnt, indeg, n);
  k_scan1<<<nb, 256, 0, stream>>>(indeg, rp, partials, n);
  k_scan2<<<1, 512, 0, stream>>>(partials, nb);
  k_scan3<<<nb, 256, 0, stream>>>(indeg, rp, partials, dinv, n);
  k_bfill<<<B, 256, 0, stream>>>(ebuf, boff, bcnt, rp, csr, n);
  k_wconv<<<64, 256, 0, stream>>>(W1, Wt1);
  k_wconv<<<64, 256, 0, stream>>>(W2, Wt2);

  int gemm_blocks = (n + 63) / 64;
  int agg_blocks = (n * 32 + 255) / 256;

  k_mgemm<0><<<gemm_blocks, 256, 0, stream>>>(emb, x_idx, Wt1, dinv, h16, n);
  k_agg<<<agg_blocks, 256, 0, stream>>>(h16, rp, indeg, csr, dinv, b1, x16, n, 1, 1);
  k_mgemm<1><<<gemm_blocks, 256, 0, stream>>>(x16, nullptr, Wt2, dinv, h16, n);
  k_agg<<<agg_blocks, 256, 0, stream>>>(h16, rp, indeg, csr, dinv, b2, outp, n, 0, 0);
}